// Round 3
// baseline (143.732 us; speedup 1.0000x reference)
//
#include <hip/hip_runtime.h>

constexpr int HID  = 20;
constexpr int NEXP = 16;
constexpr int CAP  = 20480;       // per-expert list capacity (avg 16384, +25% margin)
constexpr int BPE  = CAP / 256;   // 80 blocks (of 256 thr) per expert
constexpr int K1_ROUNDS = 8;      // samples per lane in bucket kernel

__device__ __forceinline__ float silu(float v) {
    float e = __expf(-v);
    return v * __builtin_amdgcn_rcpf(1.0f + e);
}

// region index per reference _region_mask: first cell lower bound inclusive,
// upper bounds inclusive, outside [-4,4] (or NaN) -> -1 (=> output 0)
__device__ __forceinline__ int cell_idx(float v) {
    if (!(v >= -4.0f))  return -1;   // also catches NaN
    if (v <= -0.674f)   return 0;
    if (v <= 0.0f)      return 1;
    if (v <= 0.674f)    return 2;
    if (v <= 4.0f)      return 3;
    return -1;
}

// ---------------- kernel 1: bucket samples into per-expert lists ----------------
__global__ __launch_bounds__(256) void bucket_kernel(
    const float* __restrict__ x, int n_total,
    int* __restrict__ gcnt, int* __restrict__ lists,
    float* __restrict__ out)
{
    const int tid  = threadIdx.x;
    const int lane = tid & 63;
    const int wid  = (blockIdx.x * 256 + tid) >> 6;    // global wave id
    const int base = wid * (K1_ROUNDS * 64);
    const unsigned long long lmask = (1ull << lane) - 1ull;

    const float2* x2 = reinterpret_cast<const float2*>(x);

    unsigned int epack[2] = {0u, 0u};   // 8 rounds x 8-bit expert id
    int cnt[NEXP];
    #pragma unroll
    for (int k = 0; k < NEXP; ++k) cnt[k] = 0;

    // phase A: classify + per-wave histogram (all array indices compile-time)
    #pragma unroll
    for (int r = 0; r < K1_ROUNDS; ++r) {
        const int n = base + r * 64 + lane;
        int e = 17;                              // 17 = no sample
        if (n < n_total) {
            const float2 xv = x2[n];             // coalesced 8B/lane
            const int c = cell_idx(xv.x), rr = cell_idx(xv.y);
            e = ((c | rr) >= 0) ? (c * 4 + rr) : 16;   // 16 = out of range
        }
        epack[r >> 2] |= (unsigned)e << ((r & 3) * 8);
        #pragma unroll
        for (int k = 0; k < NEXP; ++k) {
            const unsigned long long m = __ballot(e == k);
            cnt[k] += (int)__popcll(m);          // wave-uniform
        }
    }

    // reserve global ranges: one atomic per wave per non-empty expert
    int wb[NEXP];
    #pragma unroll
    for (int k = 0; k < NEXP; ++k) {
        int old = 0;
        if (lane == 0 && cnt[k] > 0) old = atomicAdd(&gcnt[k], cnt[k]);
        wb[k] = __shfl(old, 0);
    }

    // phase B: stable ranks -> scatter sample indices
    int roff[NEXP];
    #pragma unroll
    for (int k = 0; k < NEXP; ++k) roff[k] = 0;

    #pragma unroll
    for (int r = 0; r < K1_ROUNDS; ++r) {
        const int e = (int)((epack[r >> 2] >> ((r & 3) * 8)) & 0xFFu);
        const int n = base + r * 64 + lane;
        int slot = -1;
        #pragma unroll
        for (int k = 0; k < NEXP; ++k) {
            const unsigned long long m = __ballot(e == k);
            if (e == k) slot = wb[k] + roff[k] + (int)__popcll(m & lmask);
            roff[k] += (int)__popcll(m);
        }
        if (e < NEXP)       lists[e * CAP + slot] = n;
        else if (e == 16)   out[n] = 0.0f;       // out-of-range -> mask sum = 0
    }
}

// ---------------- kernel 2: evaluate, one expert per block ----------------
// weights read at wave-uniform addresses from read-only memory -> s_load + SGPR
__device__ __forceinline__ void layer20g(float (&h)[HID],
                                         const float* __restrict__ Wm,
                                         const float* __restrict__ bv) {
    float acc[HID];
    #pragma unroll
    for (int j = 0; j < HID; ++j) acc[j] = bv[j];
    #pragma unroll
    for (int k = 0; k < HID; ++k) {
        const float hk = h[k];
        #pragma unroll
        for (int j = 0; j < HID; ++j)
            acc[j] = fmaf(hk, Wm[k * HID + j], acc[j]);   // v_fmac v, s, v
    }
    #pragma unroll
    for (int j = 0; j < HID; ++j) h[j] = silu(acc[j]);
}

__global__ __launch_bounds__(256) void eval_kernel(
    const float* __restrict__ x,
    const float* __restrict__ W1, const float* __restrict__ b1,
    const float* __restrict__ W2, const float* __restrict__ b2,
    const float* __restrict__ W3, const float* __restrict__ b3,
    const float* __restrict__ W4, const float* __restrict__ b4,
    const float* __restrict__ W5, const float* __restrict__ b5,
    const int* __restrict__ gcnt, const int* __restrict__ lists,
    float* __restrict__ out)
{
    const int e     = blockIdx.x / BPE;           // SGPR-uniform expert id
    const int cbase = (blockIdx.x % BPE) * 256;
    const int ce    = gcnt[e];                    // scalar load
    if (cbase >= ce) return;                      // uniform early-exit

    const int  slot   = cbase + threadIdx.x;
    const bool active = slot < ce;
    const int  idx    = lists[e * CAP + (active ? slot : 0)];

    const float2 xv = reinterpret_cast<const float2*>(x)[idx];  // L2-resident gather

    const float* w1 = W1 + e * (2 * HID);
    const float* v1 = b1 + e * HID;
    const float* w2 = W2 + e * (HID * HID);
    const float* v2 = b2 + e * HID;
    const float* w3 = W3 + e * (HID * HID);
    const float* v3 = b3 + e * HID;
    const float* w4 = W4 + e * (HID * HID);
    const float* v4 = b4 + e * HID;
    const float* w5 = W5 + e * HID;
    const float* v5 = b5 + e;

    float h[HID];
    // layer 1: 2 -> 20
    #pragma unroll
    for (int j = 0; j < HID; ++j)
        h[j] = silu(fmaf(xv.x, w1[j], fmaf(xv.y, w1[HID + j], v1[j])));
    // layers 2..4: 20 -> 20
    layer20g(h, w2, v2);
    layer20g(h, w3, v3);
    layer20g(h, w4, v4);
    // layer 5: 20 -> 1
    float acc = v5[0];
    #pragma unroll
    for (int k = 0; k < HID; ++k) acc = fmaf(h[k], w5[k], acc);

    if (active) out[idx] = acc;   // 4B scatter, runs are mostly sequential
}

extern "C" void kernel_launch(void* const* d_in, const int* in_sizes, int n_in,
                              void* d_out, int out_size, void* d_ws, size_t ws_size,
                              hipStream_t stream) {
    const float* x  = (const float*)d_in[0];
    const float* W1 = (const float*)d_in[1];
    const float* b1 = (const float*)d_in[2];
    const float* W2 = (const float*)d_in[3];
    const float* b2 = (const float*)d_in[4];
    const float* W3 = (const float*)d_in[5];
    const float* b3 = (const float*)d_in[6];
    const float* W4 = (const float*)d_in[7];
    const float* b4 = (const float*)d_in[8];
    const float* W5 = (const float*)d_in[9];
    const float* b5 = (const float*)d_in[10];
    float* out = (float*)d_out;

    const int n_total = in_sizes[0] / 2;          // 262144 samples

    int* gcnt  = (int*)d_ws;                      // 16 counters (256B reserved)
    int* lists = (int*)d_ws + 64;                 // 16 x CAP sample indices

    hipMemsetAsync(d_ws, 0, 256, stream);         // zero counters each call

    const int k1_blocks = (n_total + (K1_ROUNDS * 256) - 1) / (K1_ROUNDS * 256); // 128
    hipLaunchKernelGGL(bucket_kernel, dim3(k1_blocks), dim3(256), 0, stream,
                       x, n_total, gcnt, lists, out);

    hipLaunchKernelGGL(eval_kernel, dim3(NEXP * BPE), dim3(256), 0, stream,
                       x, W1, b1, W2, b2, W3, b3, W4, b4, W5, b5,
                       gcnt, lists, out);
}

// Round 4
// 51.663 us; speedup vs baseline: 2.7821x; 2.7821x over previous
//
#include <hip/hip_runtime.h>

constexpr int HID  = 20;
constexpr int NEXP = 16;
constexpr int CAP  = 20480;       // per-expert list capacity (avg 16384, +25% margin)
constexpr int BPE  = CAP / 256;   // 80 eval blocks (of 256 thr) per expert
constexpr int ROUNDS = 4;         // samples per lane in bucket kernel
constexpr int GSTRIDE = 16;       // ints between gcnt counters -> one 64B line each

__device__ __forceinline__ float silu(float v) {
    float e = __expf(-v);
    return v * __builtin_amdgcn_rcpf(1.0f + e);
}

// region index per reference _region_mask: first cell lower bound inclusive,
// upper bounds inclusive, outside [-4,4] (or NaN) -> -1 (=> output 0)
__device__ __forceinline__ int cell_idx(float v) {
    if (!(v >= -4.0f))  return -1;   // also catches NaN
    if (v <= -0.674f)   return 0;
    if (v <= 0.0f)      return 1;
    if (v <= 0.674f)    return 2;
    if (v <= 4.0f)      return 3;
    return -1;
}

// ---------------- kernel 1: bucket samples into per-expert lists ----------------
// 256 blocks x 256 thr x 4 samples. One vector atomic per (block,expert), padded lines.
__global__ __launch_bounds__(256) void bucket_kernel(
    const float* __restrict__ x, int n_total,
    int* __restrict__ gcnt, int* __restrict__ lists,
    float* __restrict__ out)
{
    __shared__ int wcnt[4][NEXP];
    __shared__ int wbase[4][NEXP];

    const int tid  = threadIdx.x;
    const int lane = tid & 63;
    const int wv   = tid >> 6;
    const int base = blockIdx.x * (4 * ROUNDS * 64) + wv * (ROUNDS * 64);
    const unsigned long long lmask = (1ull << lane) - 1ull;
    const float2* x2 = reinterpret_cast<const float2*>(x);

    unsigned int epack = 0;          // 4 rounds x 8-bit expert id
    int cnt[NEXP];
    #pragma unroll
    for (int k = 0; k < NEXP; ++k) cnt[k] = 0;

    // phase A: classify + per-wave histogram (independent loads -> pipelined)
    #pragma unroll
    for (int r = 0; r < ROUNDS; ++r) {
        const int n = base + r * 64 + lane;
        int e = 17;                              // 17 = no sample
        if (n < n_total) {
            const float2 xv = x2[n];             // coalesced 8B/lane
            const int c = cell_idx(xv.x), rr = cell_idx(xv.y);
            e = ((c | rr) >= 0) ? (c * 4 + rr) : 16;   // 16 = out of range
        }
        epack |= (unsigned)e << (r * 8);
        #pragma unroll
        for (int k = 0; k < NEXP; ++k)
            cnt[k] += (int)__popcll(__ballot(e == k));   // wave-uniform
    }

    if (lane == 0) {
        #pragma unroll
        for (int k = 0; k < NEXP; ++k) wcnt[wv][k] = cnt[k];   // compile-time idx
    }
    __syncthreads();

    // one atomic per expert, 16 lanes in parallel, each on its own cache line
    if (tid < NEXP) {
        const int c0 = wcnt[0][tid], c1 = wcnt[1][tid],
                  c2 = wcnt[2][tid], c3 = wcnt[3][tid];
        const int tot = c0 + c1 + c2 + c3;
        int old = 0;
        if (tot) old = atomicAdd(&gcnt[tid * GSTRIDE], tot);
        wbase[0][tid] = old;
        wbase[1][tid] = old + c0;
        wbase[2][tid] = old + c0 + c1;
        wbase[3][tid] = old + c0 + c1 + c2;
    }
    __syncthreads();

    int wb[NEXP], roff[NEXP];
    #pragma unroll
    for (int k = 0; k < NEXP; ++k) { wb[k] = wbase[wv][k]; roff[k] = 0; }

    // phase B: stable ranks -> scatter sample indices
    #pragma unroll
    for (int r = 0; r < ROUNDS; ++r) {
        const int e = (int)((epack >> (r * 8)) & 0xFFu);
        const int n = base + r * 64 + lane;
        int slot = -1;
        #pragma unroll
        for (int k = 0; k < NEXP; ++k) {
            const unsigned long long m = __ballot(e == k);
            if (e == k) slot = wb[k] + roff[k] + (int)__popcll(m & lmask);
            roff[k] += (int)__popcll(m);
        }
        if (e < NEXP)     lists[e * CAP + slot] = n;
        else if (e == 16) out[n] = 0.0f;       // out-of-range -> masked sum = 0
    }
}

// ---------------- kernel 2: evaluate, one expert per block ----------------
// weights read at wave-uniform addresses from read-only memory -> s_load + SGPR operand
__device__ __forceinline__ void layer20g(float (&h)[HID],
                                         const float* __restrict__ Wm,
                                         const float* __restrict__ bv) {
    float acc[HID];
    #pragma unroll
    for (int j = 0; j < HID; ++j) acc[j] = bv[j];
    #pragma unroll
    for (int k = 0; k < HID; ++k) {
        const float hk = h[k];
        #pragma unroll
        for (int j = 0; j < HID; ++j)
            acc[j] = fmaf(hk, Wm[k * HID + j], acc[j]);   // v_fmac v, s, v
    }
    #pragma unroll
    for (int j = 0; j < HID; ++j) h[j] = silu(acc[j]);
}

__global__ __launch_bounds__(256) void eval_kernel(
    const float* __restrict__ x,
    const float* __restrict__ W1, const float* __restrict__ b1,
    const float* __restrict__ W2, const float* __restrict__ b2,
    const float* __restrict__ W3, const float* __restrict__ b3,
    const float* __restrict__ W4, const float* __restrict__ b4,
    const float* __restrict__ W5, const float* __restrict__ b5,
    const int* __restrict__ gcnt, const int* __restrict__ lists,
    float* __restrict__ out)
{
    const int e     = blockIdx.x / BPE;           // SGPR-uniform expert id
    const int cbase = (blockIdx.x % BPE) * 256;
    const int ce    = gcnt[e * GSTRIDE];          // scalar load
    if (cbase >= ce) return;                      // uniform early-exit

    const int  slot   = cbase + threadIdx.x;
    const bool active = slot < ce;
    const int  idx    = lists[e * CAP + (active ? slot : 0)];

    const float2 xv = reinterpret_cast<const float2*>(x)[idx];  // L2-resident gather

    const float* w1 = W1 + e * (2 * HID);
    const float* v1 = b1 + e * HID;
    const float* w2 = W2 + e * (HID * HID);
    const float* v2 = b2 + e * HID;
    const float* w3 = W3 + e * (HID * HID);
    const float* v3 = b3 + e * HID;
    const float* w4 = W4 + e * (HID * HID);
    const float* v4 = b4 + e * HID;
    const float* w5 = W5 + e * HID;
    const float* v5 = b5 + e;

    float h[HID];
    // layer 1: 2 -> 20
    #pragma unroll
    for (int j = 0; j < HID; ++j)
        h[j] = silu(fmaf(xv.x, w1[j], fmaf(xv.y, w1[HID + j], v1[j])));
    // layers 2..4: 20 -> 20
    layer20g(h, w2, v2);
    layer20g(h, w3, v3);
    layer20g(h, w4, v4);
    // layer 5: 20 -> 1
    float acc = v5[0];
    #pragma unroll
    for (int k = 0; k < HID; ++k) acc = fmaf(h[k], w5[k], acc);

    if (active) out[idx] = acc;   // 4B scatter, runs are mostly sequential
}

extern "C" void kernel_launch(void* const* d_in, const int* in_sizes, int n_in,
                              void* d_out, int out_size, void* d_ws, size_t ws_size,
                              hipStream_t stream) {
    const float* x  = (const float*)d_in[0];
    const float* W1 = (const float*)d_in[1];
    const float* b1 = (const float*)d_in[2];
    const float* W2 = (const float*)d_in[3];
    const float* b2 = (const float*)d_in[4];
    const float* W3 = (const float*)d_in[5];
    const float* b3 = (const float*)d_in[6];
    const float* W4 = (const float*)d_in[7];
    const float* b4 = (const float*)d_in[8];
    const float* W5 = (const float*)d_in[9];
    const float* b5 = (const float*)d_in[10];
    float* out = (float*)d_out;

    const int n_total = in_sizes[0] / 2;          // 262144 samples

    int* gcnt  = (int*)d_ws;                      // 16 counters, 64B apart
    int* lists = (int*)d_ws + NEXP * GSTRIDE;     // 16 x CAP sample indices

    hipMemsetAsync(d_ws, 0, NEXP * GSTRIDE * sizeof(int), stream);

    const int k1_blocks = (n_total + (ROUNDS * 256) - 1) / (ROUNDS * 256); // 256
    hipLaunchKernelGGL(bucket_kernel, dim3(k1_blocks), dim3(256), 0, stream,
                       x, n_total, gcnt, lists, out);

    hipLaunchKernelGGL(eval_kernel, dim3(NEXP * BPE), dim3(256), 0, stream,
                       x, W1, b1, W2, b2, W3, b3, W4, b4, W5, b5,
                       gcnt, lists, out);
}